// Round 6
// baseline (1576.196 us; speedup 1.0000x reference)
//
#include <hip/hip_runtime.h>
#include <hip/hip_bf16.h>

// BitNet FFN: LN -> act_quant/ternary-W matmul -> GELU(erf) -> act_quant/ternary-W matmul
// Shapes: x[4,4096,2048] f32, w1[8192,2048], w2[2048,8192], out [16384,2048] f32.
// R6: rotated software-pipelined K-loop. Two fragment register sets; ks1 reads
// issue under MFMA(ks0), next tile's ks0 reads issue under MFMA(ks1) via
// counted lgkmcnt (in-order DS retire). Accumulation order unchanged ->
// output bit-identical to R4/R5 (absmax 2.539e-2 canary).
// Peak ws 353 MiB; d_out doubles as f32 GELU staging per M-chunk.

typedef __attribute__((ext_vector_type(8))) short short8;
typedef __attribute__((ext_vector_type(4))) float floatx4;

#define D_DIM 2048
#define H_DIM 8192
#define M_DIM 16384
#define MCHUNK 4096

// ---------- small helpers ----------
__device__ __forceinline__ unsigned short f2bf(float f) {
  unsigned int u = __builtin_bit_cast(unsigned int, f);
  u += 0x7FFFu + ((u >> 16) & 1u);   // RNE; inputs here are never NaN
  return (unsigned short)(u >> 16);
}

__device__ __forceinline__ float block_sum(float v, float* buf) {
#pragma unroll
  for (int o = 32; o > 0; o >>= 1) v += __shfl_down(v, o, 64);
  const int lane = threadIdx.x & 63, w = threadIdx.x >> 6;
  if (lane == 0) buf[w] = v;
  __syncthreads();
  float r = buf[0] + buf[1] + buf[2] + buf[3];
  __syncthreads();
  return r;
}
__device__ __forceinline__ float block_max(float v, float* buf) {
#pragma unroll
  for (int o = 32; o > 0; o >>= 1) v = fmaxf(v, __shfl_down(v, o, 64));
  const int lane = threadIdx.x & 63, w = threadIdx.x >> 6;
  if (lane == 0) buf[w] = v;
  __syncthreads();
  float r = fmaxf(fmaxf(buf[0], buf[1]), fmaxf(buf[2], buf[3]));
  __syncthreads();
  return r;
}

__device__ __forceinline__ void lds16(const unsigned short* g, unsigned short* l) {
  __builtin_amdgcn_global_load_lds(
      (const __attribute__((address_space(1))) unsigned int*)g,
      (__attribute__((address_space(3))) unsigned int*)l, 16, 0, 0);
}

// ---------- weight abs-mean (deterministic two-stage) ----------
__global__ __launch_bounds__(256) void absmean_partial(const float* __restrict__ w,
                                                       int n, double* __restrict__ part) {
  __shared__ float buf[4];
  float s = 0.0f;
  const long stride = (long)gridDim.x * 256 * 4;
  for (long i = ((long)blockIdx.x * 256 + threadIdx.x) * 4; i < n; i += stride) {
    float4 v = *(const float4*)(w + i);
    s += fabsf(v.x) + fabsf(v.y) + fabsf(v.z) + fabsf(v.w);
  }
  float r = block_sum(s, buf);
  if (threadIdx.x == 0) part[blockIdx.x] = (double)r;
}

__global__ __launch_bounds__(256) void absmean_final(const double* __restrict__ part,
                                                     int nb, double n, double* __restrict__ out) {
  __shared__ double buf[4];
  double s = 0.0;
  for (int i = threadIdx.x; i < nb; i += 256) s += part[i];
#pragma unroll
  for (int o = 32; o > 0; o >>= 1) s += __shfl_down(s, o, 64);
  const int lane = threadIdx.x & 63, w = threadIdx.x >> 6;
  if (lane == 0) buf[w] = s;
  __syncthreads();
  if (threadIdx.x == 0) out[0] = (buf[0] + buf[1] + buf[2] + buf[3]) / n;
}

// ---------- ternary weight quant: t = clip(rint(w*s),-1,1), stored as bf16 ----------
__global__ __launch_bounds__(256) void wquant_kernel(const float* __restrict__ w,
                                                     const double* __restrict__ mean,
                                                     unsigned short* __restrict__ wq, int n) {
  long i = ((long)blockIdx.x * 256 + threadIdx.x) * 4;
  if (i >= n) return;
  const float s = 1.0f / (float)fmax(mean[0], 1e-5);
  float4 v = *(const float4*)(w + i);
  ushort4 q;
  q.x = f2bf(fminf(fmaxf(rintf(v.x * s), -1.f), 1.f));
  q.y = f2bf(fminf(fmaxf(rintf(v.y * s), -1.f), 1.f));
  q.z = f2bf(fminf(fmaxf(rintf(v.z * s), -1.f), 1.f));
  q.w = f2bf(fminf(fmaxf(rintf(v.w * s), -1.f), 1.f));
  *(ushort4*)(wq + i) = q;
}

// ---------- fused LayerNorm + per-token int8 absmax quant ----------
__global__ __launch_bounds__(256) void ln_quant_kernel(const float* __restrict__ x,
                                                       const float* __restrict__ gamma,
                                                       const float* __restrict__ beta,
                                                       unsigned short* __restrict__ aq,
                                                       float* __restrict__ ds) {
  __shared__ float buf[4];
  const int t = threadIdx.x;
  const long row = blockIdx.x;
  const float* xr = x + row * (long)D_DIM;
  float v[8];
  *(float4*)(v)     = *(const float4*)(xr + t * 8);
  *(float4*)(v + 4) = *(const float4*)(xr + t * 8 + 4);
  float s = 0.f;
#pragma unroll
  for (int i = 0; i < 8; ++i) s += v[i];
  s = block_sum(s, buf);
  const float mu = s * (1.0f / 2048.0f);
  float sq = 0.f;
#pragma unroll
  for (int i = 0; i < 8; ++i) { float d = v[i] - mu; sq += d * d; }
  sq = block_sum(sq, buf);
  const float inv = 1.0f / sqrtf(sq * (1.0f / 2048.0f) + 1e-5f);
  float gam[8], bet[8];
  *(float4*)(gam)     = *(const float4*)(gamma + t * 8);
  *(float4*)(gam + 4) = *(const float4*)(gamma + t * 8 + 4);
  *(float4*)(bet)     = *(const float4*)(beta + t * 8);
  *(float4*)(bet + 4) = *(const float4*)(beta + t * 8 + 4);
  float xn[8]; float am = 0.f;
#pragma unroll
  for (int i = 0; i < 8; ++i) {
    xn[i] = (v[i] - mu) * inv * gam[i] + bet[i];
    am = fmaxf(am, fabsf(xn[i]));
  }
  am = block_max(am, buf);
  am = fmaxf(am, 1e-5f);
  const float qs = 127.0f / am;
  __align__(16) unsigned short q[8];
#pragma unroll
  for (int i = 0; i < 8; ++i)
    q[i] = f2bf(fminf(fmaxf(rintf(xn[i] * qs), -128.f), 127.f));
  *(ushort4*)(aq + row * D_DIM + t * 8)     = *(ushort4*)(q);
  *(ushort4*)(aq + row * D_DIM + t * 8 + 4) = *(ushort4*)(q + 4);
  if (t == 0) ds[row] = am / 127.0f;
}

// ---------- per-token re-quant from f32 h chunk -> dense bf16 ints ----------
__global__ __launch_bounds__(256) void hquant32_kernel(const float* __restrict__ src,
                                                       unsigned short* __restrict__ dst,
                                                       float* __restrict__ ds2) {
  __shared__ float buf[4];
  const int t = threadIdx.x;
  const long row = blockIdx.x;
  const float* sr = src + row * (long)H_DIM;
  float v[4][8];
#pragma unroll
  for (int c = 0; c < 4; ++c) {
    *(float4*)(v[c])     = *(const float4*)(sr + (c * 256 + t) * 8);
    *(float4*)(v[c] + 4) = *(const float4*)(sr + (c * 256 + t) * 8 + 4);
  }
  float am = 0.f;
#pragma unroll
  for (int c = 0; c < 4; ++c)
#pragma unroll
    for (int i = 0; i < 8; ++i) am = fmaxf(am, fabsf(v[c][i]));
  am = block_max(am, buf);
  am = fmaxf(am, 1e-5f);
  const float qs = 127.0f / am;
  unsigned short* dr = dst + row * (long)H_DIM;
#pragma unroll
  for (int c = 0; c < 4; ++c) {
    short8 o;
#pragma unroll
    for (int i = 0; i < 8; ++i)
      o[i] = (short)f2bf(fminf(fmaxf(rintf(v[c][i] * qs), -128.f), 127.f));
    *(short8*)(dr + (c * 256 + t) * 8) = o;
  }
  if (t == 0) ds2[row] = am / 127.0f;
}

// ---------- fragment read + MFMA cluster helpers ----------
__device__ __forceinline__ void read_frags(const unsigned short* pA, const unsigned short* pB,
                                           int wr, int wcn, int frow, int g,
                                           short8 af[8], short8 bf[4]) {
#pragma unroll
  for (int m = 0; m < 8; ++m)
    af[m] = *(const short8*)&pA[(wr * 128 + m * 16 + frow) * 64 + g * 8];
#pragma unroll
  for (int n = 0; n < 4; ++n)
    bf[n] = *(const short8*)&pB[(wcn * 64 + n * 16 + frow) * 64 + g * 8];
}

__device__ __forceinline__ void mfma32(const short8 af[8], const short8 bf[4],
                                       floatx4 acc[8][4]) {
#pragma unroll
  for (int m = 0; m < 8; ++m)
#pragma unroll
    for (int n = 0; n < 4; ++n)
      acc[m][n] = __builtin_amdgcn_mfma_f32_16x16x32_bf16(af[m], bf[n], acc[m][n], 0, 0, 0);
}

// ---------- 256x256 BK=64 rotated-pipeline GEMM, A[M,K] x B[N,K]^T ----------
// 8 waves (2M x 4N), each owns 128x64 output. Double-buffered 128KiB LDS.
// T2 granule swizzle: LDS granule g holds global granule g^(row&7) (both sides).
// EPI==1: dequant+bias+exact GELU -> f32 outf   (GEMM1 chunk)
// EPI==2: dequant+bias            -> f32 outf   (GEMM2)
template <int EPI>
__global__ __launch_bounds__(512, 1) void gemm256_kernel(
    const unsigned short* __restrict__ A,
    const unsigned short* __restrict__ Bm,
    const float* __restrict__ dsA,
    const double* __restrict__ meanw,
    const float* __restrict__ bias,
    float* __restrict__ outf,
    int NBX, int N, int K) {
  __shared__ __align__(16) unsigned short smA[2][256 * 64];
  __shared__ __align__(16) unsigned short smB[2][256 * 64];
  const int tid = threadIdx.x;
  const int lane = tid & 63;
  const int wid = tid >> 6;
  const int wr = wid >> 2;    // 0..1 (M quadrant of 128 rows)
  const int wcn = wid & 3;    // 0..3 (N quadrant of 64 cols)

  // T1: XCD-aware bijective block swizzle (gridDim.x % 8 == 0 here: 512)
  const int cpx = gridDim.x >> 3;
  const int swz = ((int)blockIdx.x & 7) * cpx + ((int)blockIdx.x >> 3);
  const int bx = swz % NBX, by = swz / NBX;

  const long r0 = (long)by * 256;
  const long c0 = (long)bx * 256;

  // staging geometry: source granule pre-swizzled so linear global_load_lds
  // dest realizes the XOR layout (rule #21: both-sides-or-neither).
  const int sr = tid >> 3;                        // row 0..63 within 64-row block
  const int gn = (tid & 7) ^ (sr & 7);            // pre-swizzled source granule
  const unsigned short* gA = A + (r0 + sr) * (long)K + gn * 8;
  const unsigned short* gB = Bm + (c0 + sr) * (long)K + gn * 8;
  const long rowK64 = 64l * (long)K;

  // fragment-read geometry
  const int frow = lane & 15;
  const int fg0 = (lane >> 4) ^ (lane & 7);       // swizzled granule for ks=0

  floatx4 acc[8][4] = {};
  short8 af0[8], bf0[4], af1[8], bf1[4];
  const int nk = K >> 6;                          // BK = 64

#define STAGE256(kt_, c_) {                                           \
    const long ko_ = (long)(kt_) * 64;                                \
    unsigned short* dA_ = &smA[c_][tid * 8];                          \
    unsigned short* dB_ = &smB[c_][tid * 8];                          \
    lds16(gA + ko_,              dA_);                                \
    lds16(gA + ko_ + rowK64,     dA_ + 4096);                         \
    lds16(gA + ko_ + 2 * rowK64, dA_ + 8192);                         \
    lds16(gA + ko_ + 3 * rowK64, dA_ + 12288);                        \
    lds16(gB + ko_,              dB_);                                \
    lds16(gB + ko_ + rowK64,     dB_ + 4096);                         \
    lds16(gB + ko_ + 2 * rowK64, dB_ + 8192);                         \
    lds16(gB + ko_ + 3 * rowK64, dB_ + 12288);                        \
  }

  // prologue: stage K-tiles 0,1; wait tile 0 (8 of 16 retire); publish;
  // issue tile-0 ks0 fragment reads.
  STAGE256(0, 0);
  STAGE256(1, 1);
  asm volatile("s_waitcnt vmcnt(8)" ::: "memory");
  __builtin_amdgcn_s_barrier();
  __builtin_amdgcn_sched_barrier(0);
  read_frags(smA[0], smB[0], wr, wcn, frow, fg0, af0, bf0);
  __builtin_amdgcn_sched_barrier(0);

  for (int kt = 0; kt < nk; ++kt) {
    const int c = kt & 1;
    const unsigned short* pA = smA[c];
    const unsigned short* pB = smB[c];

    // 1. issue ks1 reads (set1) -- fly under MFMA(set0)
    read_frags(pA, pB, wr, wcn, frow, fg0 ^ 4, af1, bf1);
    __builtin_amdgcn_sched_barrier(0);
    // 2. set0 complete (in-order DS retire: <=12 outstanding = set1's)
    asm volatile("s_waitcnt lgkmcnt(12)" ::: "memory");
    __builtin_amdgcn_sched_barrier(0);
    // 3. MFMA ks0
    __builtin_amdgcn_s_setprio(1);
    mfma32(af0, bf0, acc);
    __builtin_amdgcn_s_setprio(0);
    __builtin_amdgcn_sched_barrier(0);
    // 4. set1 complete (all this wave's LDS reads done)
    asm volatile("s_waitcnt lgkmcnt(0)" ::: "memory");
    __builtin_amdgcn_sched_barrier(0);
    // 5. WAR barrier: every wave done reading buf c
    __builtin_amdgcn_s_barrier();
    __builtin_amdgcn_sched_barrier(0);
    // 6. stage tile kt+2 into buf c
    if (kt + 2 < nk) STAGE256(kt + 2, c);
    // 7. wait tile kt+1's loads (leave kt+2's 8 in flight); publish
    if (kt + 2 < nk) {
      asm volatile("s_waitcnt vmcnt(8)" ::: "memory");
    } else if (kt + 1 < nk) {
      asm volatile("s_waitcnt vmcnt(0)" ::: "memory");
    }
    if (kt + 1 < nk) {
      __builtin_amdgcn_s_barrier();
      __builtin_amdgcn_sched_barrier(0);
      // 8. issue next tile's ks0 reads (set0) -- fly under MFMA(set1)
      read_frags(smA[c ^ 1], smB[c ^ 1], wr, wcn, frow, fg0, af0, bf0);
      __builtin_amdgcn_sched_barrier(0);
    }
    // 9. MFMA ks1
    __builtin_amdgcn_s_setprio(1);
    mfma32(af1, bf1, acc);
    __builtin_amdgcn_s_setprio(0);
  }
#undef STAGE256

  // ---- epilogue ----
  const float sw = (float)fmax(meanw[0], 1e-5);
#pragma unroll
  for (int m = 0; m < 8; ++m) {
#pragma unroll
    for (int j = 0; j < 4; ++j) {
      const long row = r0 + wr * 128 + m * 16 + (lane >> 4) * 4 + j;
      const float sa = dsA[row] * sw;
#pragma unroll
      for (int n = 0; n < 4; ++n) {
        const long col = c0 + wcn * 64 + n * 16 + (lane & 15);
        float v = acc[m][n][j] * sa + bias[col];
        if (EPI == 1) {
          float gl = 0.5f * v * (1.0f + erff(v * 0.70710678118654752f));
          outf[row * (long)N + col] = gl;
        } else {
          outf[row * (long)N + col] = v;
        }
      }
    }
  }
}

extern "C" void kernel_launch(void* const* d_in, const int* in_sizes, int n_in,
                              void* d_out, int out_size, void* d_ws, size_t ws_size,
                              hipStream_t stream) {
  const float* x     = (const float*)d_in[0];
  const float* gamma = (const float*)d_in[1];
  const float* beta  = (const float*)d_in[2];
  const float* w1    = (const float*)d_in[3];
  const float* b1    = (const float*)d_in[4];
  const float* w2    = (const float*)d_in[5];
  const float* b2    = (const float*)d_in[6];

  char* ws = (char*)d_ws;
  // meta (<256K): part1@0, part2@16K, means@32K, ds1@64K, ds2@128K
  // [1M)      wq  32M  (wq1, reused for wq2 after last GEMM1 chunk)
  // [1M+32M)  aq  64M
  // [1M+96M)  hq 256M  (dense quantized h, bf16 ints)
  // peak 353 MiB.  d_out (128M) doubles as f32 GELU staging per M-chunk.
  double* part1 = (double*)(ws + 0);
  double* part2 = (double*)(ws + 16384);
  double* means = (double*)(ws + 32768);
  float* ds1  = (float*)(ws + 65536);
  float* ds2  = (float*)(ws + 131072);
  unsigned short* wq = (unsigned short*)(ws + 1048576l);
  unsigned short* aq = (unsigned short*)(ws + 34603008l);
  unsigned short* hq = (unsigned short*)(ws + 101711872l);

  const int NW = 16777216;  // elements in each weight matrix
  float* hstage = (float*)d_out;  // 4096 x 8192 f32 = 128 MiB, dead until GEMM2

  absmean_partial<<<2048, 256, 0, stream>>>(w1, NW, part1);
  absmean_partial<<<2048, 256, 0, stream>>>(w2, NW, part2);
  absmean_final<<<1, 256, 0, stream>>>(part1, 2048, (double)NW, means + 0);
  absmean_final<<<1, 256, 0, stream>>>(part2, 2048, (double)NW, means + 1);
  wquant_kernel<<<16384, 256, 0, stream>>>(w1, means + 0, wq, NW);
  ln_quant_kernel<<<16384, 256, 0, stream>>>(x, gamma, beta, aq, ds1);

  // GEMM1 in 4 M-chunks: f32 gelu -> d_out staging, requant -> dense hq
  for (int c = 0; c < 4; ++c) {
    const long r0 = (long)c * MCHUNK;
    gemm256_kernel<1><<<(H_DIM / 256) * (MCHUNK / 256), 512, 0, stream>>>(
        aq + r0 * D_DIM, wq, ds1 + r0, means + 0, b1, hstage,
        H_DIM / 256, H_DIM, D_DIM);
    hquant32_kernel<<<MCHUNK, 256, 0, stream>>>(
        hstage, hq + r0 * H_DIM, ds2 + r0);
  }

  // wq slot now free: quantize w2 into it
  wquant_kernel<<<16384, 256, 0, stream>>>(w2, means + 1, wq, NW);

  // GEMM2: out = hq . wq2^T * (ds2*sw2) + b2
  gemm256_kernel<2><<<(D_DIM / 256) * (M_DIM / 256), 512, 0, stream>>>(
      hq, wq, ds2, means + 1, b2, (float*)d_out,
      D_DIM / 256, D_DIM, H_DIM);
}

// Round 7
// 1414.841 us; speedup vs baseline: 1.1140x; 1.1140x over previous
//
#include <hip/hip_runtime.h>
#include <hip/hip_bf16.h>

// BitNet FFN: LN -> act_quant/ternary-W matmul -> GELU(erf) -> act_quant/ternary-W matmul
// Shapes: x[4,4096,2048] f32, w1[8192,2048], w2[2048,8192], out [16384,2048] f32.
// R7: R6's rotated fragment reads (counted lgkmcnt) + R5's vmcnt placement
// (after second MFMA cluster). Both lgkm stalls and the HBM-load wait now sit
// under MFMA clusters. Accumulation order unchanged -> output bit-identical
// (absmax 2.539e-2 canary). Peak ws 353 MiB; d_out doubles as GELU staging.

typedef __attribute__((ext_vector_type(8))) short short8;
typedef __attribute__((ext_vector_type(4))) float floatx4;

#define D_DIM 2048
#define H_DIM 8192
#define M_DIM 16384
#define MCHUNK 4096

// ---------- small helpers ----------
__device__ __forceinline__ unsigned short f2bf(float f) {
  unsigned int u = __builtin_bit_cast(unsigned int, f);
  u += 0x7FFFu + ((u >> 16) & 1u);   // RNE; inputs here are never NaN
  return (unsigned short)(u >> 16);
}

__device__ __forceinline__ float block_sum(float v, float* buf) {
#pragma unroll
  for (int o = 32; o > 0; o >>= 1) v += __shfl_down(v, o, 64);
  const int lane = threadIdx.x & 63, w = threadIdx.x >> 6;
  if (lane == 0) buf[w] = v;
  __syncthreads();
  float r = buf[0] + buf[1] + buf[2] + buf[3];
  __syncthreads();
  return r;
}
__device__ __forceinline__ float block_max(float v, float* buf) {
#pragma unroll
  for (int o = 32; o > 0; o >>= 1) v = fmaxf(v, __shfl_down(v, o, 64));
  const int lane = threadIdx.x & 63, w = threadIdx.x >> 6;
  if (lane == 0) buf[w] = v;
  __syncthreads();
  float r = fmaxf(fmaxf(buf[0], buf[1]), fmaxf(buf[2], buf[3]));
  __syncthreads();
  return r;
}

__device__ __forceinline__ void lds16(const unsigned short* g, unsigned short* l) {
  __builtin_amdgcn_global_load_lds(
      (const __attribute__((address_space(1))) unsigned int*)g,
      (__attribute__((address_space(3))) unsigned int*)l, 16, 0, 0);
}

// ---------- weight abs-mean (deterministic two-stage) ----------
__global__ __launch_bounds__(256) void absmean_partial(const float* __restrict__ w,
                                                       int n, double* __restrict__ part) {
  __shared__ float buf[4];
  float s = 0.0f;
  const long stride = (long)gridDim.x * 256 * 4;
  for (long i = ((long)blockIdx.x * 256 + threadIdx.x) * 4; i < n; i += stride) {
    float4 v = *(const float4*)(w + i);
    s += fabsf(v.x) + fabsf(v.y) + fabsf(v.z) + fabsf(v.w);
  }
  float r = block_sum(s, buf);
  if (threadIdx.x == 0) part[blockIdx.x] = (double)r;
}

__global__ __launch_bounds__(256) void absmean_final(const double* __restrict__ part,
                                                     int nb, double n, double* __restrict__ out) {
  __shared__ double buf[4];
  double s = 0.0;
  for (int i = threadIdx.x; i < nb; i += 256) s += part[i];
#pragma unroll
  for (int o = 32; o > 0; o >>= 1) s += __shfl_down(s, o, 64);
  const int lane = threadIdx.x & 63, w = threadIdx.x >> 6;
  if (lane == 0) buf[w] = s;
  __syncthreads();
  if (threadIdx.x == 0) out[0] = (buf[0] + buf[1] + buf[2] + buf[3]) / n;
}

// ---------- ternary weight quant: t = clip(rint(w*s),-1,1), stored as bf16 ----------
__global__ __launch_bounds__(256) void wquant_kernel(const float* __restrict__ w,
                                                     const double* __restrict__ mean,
                                                     unsigned short* __restrict__ wq, int n) {
  long i = ((long)blockIdx.x * 256 + threadIdx.x) * 4;
  if (i >= n) return;
  const float s = 1.0f / (float)fmax(mean[0], 1e-5);
  float4 v = *(const float4*)(w + i);
  ushort4 q;
  q.x = f2bf(fminf(fmaxf(rintf(v.x * s), -1.f), 1.f));
  q.y = f2bf(fminf(fmaxf(rintf(v.y * s), -1.f), 1.f));
  q.z = f2bf(fminf(fmaxf(rintf(v.z * s), -1.f), 1.f));
  q.w = f2bf(fminf(fmaxf(rintf(v.w * s), -1.f), 1.f));
  *(ushort4*)(wq + i) = q;
}

// ---------- fused LayerNorm + per-token int8 absmax quant ----------
__global__ __launch_bounds__(256) void ln_quant_kernel(const float* __restrict__ x,
                                                       const float* __restrict__ gamma,
                                                       const float* __restrict__ beta,
                                                       unsigned short* __restrict__ aq,
                                                       float* __restrict__ ds) {
  __shared__ float buf[4];
  const int t = threadIdx.x;
  const long row = blockIdx.x;
  const float* xr = x + row * (long)D_DIM;
  float v[8];
  *(float4*)(v)     = *(const float4*)(xr + t * 8);
  *(float4*)(v + 4) = *(const float4*)(xr + t * 8 + 4);
  float s = 0.f;
#pragma unroll
  for (int i = 0; i < 8; ++i) s += v[i];
  s = block_sum(s, buf);
  const float mu = s * (1.0f / 2048.0f);
  float sq = 0.f;
#pragma unroll
  for (int i = 0; i < 8; ++i) { float d = v[i] - mu; sq += d * d; }
  sq = block_sum(sq, buf);
  const float inv = 1.0f / sqrtf(sq * (1.0f / 2048.0f) + 1e-5f);
  float gam[8], bet[8];
  *(float4*)(gam)     = *(const float4*)(gamma + t * 8);
  *(float4*)(gam + 4) = *(const float4*)(gamma + t * 8 + 4);
  *(float4*)(bet)     = *(const float4*)(beta + t * 8);
  *(float4*)(bet + 4) = *(const float4*)(beta + t * 8 + 4);
  float xn[8]; float am = 0.f;
#pragma unroll
  for (int i = 0; i < 8; ++i) {
    xn[i] = (v[i] - mu) * inv * gam[i] + bet[i];
    am = fmaxf(am, fabsf(xn[i]));
  }
  am = block_max(am, buf);
  am = fmaxf(am, 1e-5f);
  const float qs = 127.0f / am;
  __align__(16) unsigned short q[8];
#pragma unroll
  for (int i = 0; i < 8; ++i)
    q[i] = f2bf(fminf(fmaxf(rintf(xn[i] * qs), -128.f), 127.f));
  *(ushort4*)(aq + row * D_DIM + t * 8)     = *(ushort4*)(q);
  *(ushort4*)(aq + row * D_DIM + t * 8 + 4) = *(ushort4*)(q + 4);
  if (t == 0) ds[row] = am / 127.0f;
}

// ---------- per-token re-quant from f32 h chunk -> dense bf16 ints ----------
__global__ __launch_bounds__(256) void hquant32_kernel(const float* __restrict__ src,
                                                       unsigned short* __restrict__ dst,
                                                       float* __restrict__ ds2) {
  __shared__ float buf[4];
  const int t = threadIdx.x;
  const long row = blockIdx.x;
  const float* sr = src + row * (long)H_DIM;
  float v[4][8];
#pragma unroll
  for (int c = 0; c < 4; ++c) {
    *(float4*)(v[c])     = *(const float4*)(sr + (c * 256 + t) * 8);
    *(float4*)(v[c] + 4) = *(const float4*)(sr + (c * 256 + t) * 8 + 4);
  }
  float am = 0.f;
#pragma unroll
  for (int c = 0; c < 4; ++c)
#pragma unroll
    for (int i = 0; i < 8; ++i) am = fmaxf(am, fabsf(v[c][i]));
  am = block_max(am, buf);
  am = fmaxf(am, 1e-5f);
  const float qs = 127.0f / am;
  unsigned short* dr = dst + row * (long)H_DIM;
#pragma unroll
  for (int c = 0; c < 4; ++c) {
    short8 o;
#pragma unroll
    for (int i = 0; i < 8; ++i)
      o[i] = (short)f2bf(fminf(fmaxf(rintf(v[c][i] * qs), -128.f), 127.f));
    *(short8*)(dr + (c * 256 + t) * 8) = o;
  }
  if (t == 0) ds2[row] = am / 127.0f;
}

// ---------- fragment read + MFMA cluster helpers ----------
__device__ __forceinline__ void read_frags(const unsigned short* pA, const unsigned short* pB,
                                           int wr, int wcn, int frow, int g,
                                           short8 af[8], short8 bf[4]) {
#pragma unroll
  for (int m = 0; m < 8; ++m)
    af[m] = *(const short8*)&pA[(wr * 128 + m * 16 + frow) * 64 + g * 8];
#pragma unroll
  for (int n = 0; n < 4; ++n)
    bf[n] = *(const short8*)&pB[(wcn * 64 + n * 16 + frow) * 64 + g * 8];
}

__device__ __forceinline__ void mfma32(const short8 af[8], const short8 bf[4],
                                       floatx4 acc[8][4]) {
#pragma unroll
  for (int m = 0; m < 8; ++m)
#pragma unroll
    for (int n = 0; n < 4; ++n)
      acc[m][n] = __builtin_amdgcn_mfma_f32_16x16x32_bf16(af[m], bf[n], acc[m][n], 0, 0, 0);
}

// ---------- 256x256 BK=64 rotated-pipeline GEMM, A[M,K] x B[N,K]^T ----------
// 8 waves (2M x 4N), each owns 128x64 output. Double-buffered 128KiB LDS.
// T2 granule swizzle: LDS granule g holds global granule g^(row&7) (both sides).
// EPI==1: dequant+bias+exact GELU -> f32 outf   (GEMM1 chunk)
// EPI==2: dequant+bias            -> f32 outf   (GEMM2)
template <int EPI>
__global__ __launch_bounds__(512, 1) void gemm256_kernel(
    const unsigned short* __restrict__ A,
    const unsigned short* __restrict__ Bm,
    const float* __restrict__ dsA,
    const double* __restrict__ meanw,
    const float* __restrict__ bias,
    float* __restrict__ outf,
    int NBX, int N, int K) {
  __shared__ __align__(16) unsigned short smA[2][256 * 64];
  __shared__ __align__(16) unsigned short smB[2][256 * 64];
  const int tid = threadIdx.x;
  const int lane = tid & 63;
  const int wid = tid >> 6;
  const int wr = wid >> 2;    // 0..1 (M quadrant of 128 rows)
  const int wcn = wid & 3;    // 0..3 (N quadrant of 64 cols)

  // T1: XCD-aware bijective block swizzle (gridDim.x % 8 == 0 here: 512)
  const int cpx = gridDim.x >> 3;
  const int swz = ((int)blockIdx.x & 7) * cpx + ((int)blockIdx.x >> 3);
  const int bx = swz % NBX, by = swz / NBX;

  const long r0 = (long)by * 256;
  const long c0 = (long)bx * 256;

  // staging geometry: source granule pre-swizzled so linear global_load_lds
  // dest realizes the XOR layout (rule #21: both-sides-or-neither).
  const int sr = tid >> 3;                        // row 0..63 within 64-row block
  const int gn = (tid & 7) ^ (sr & 7);            // pre-swizzled source granule
  const unsigned short* gA = A + (r0 + sr) * (long)K + gn * 8;
  const unsigned short* gB = Bm + (c0 + sr) * (long)K + gn * 8;
  const long rowK64 = 64l * (long)K;

  // fragment-read geometry
  const int frow = lane & 15;
  const int fg0 = (lane >> 4) ^ (lane & 7);       // swizzled granule for ks=0

  floatx4 acc[8][4] = {};
  short8 af0[8], bf0[4], af1[8], bf1[4];
  const int nk = K >> 6;                          // BK = 64

#define STAGE256(kt_, c_) {                                           \
    const long ko_ = (long)(kt_) * 64;                                \
    unsigned short* dA_ = &smA[c_][tid * 8];                          \
    unsigned short* dB_ = &smB[c_][tid * 8];                          \
    lds16(gA + ko_,              dA_);                                \
    lds16(gA + ko_ + rowK64,     dA_ + 4096);                         \
    lds16(gA + ko_ + 2 * rowK64, dA_ + 8192);                         \
    lds16(gA + ko_ + 3 * rowK64, dA_ + 12288);                        \
    lds16(gB + ko_,              dB_);                                \
    lds16(gB + ko_ + rowK64,     dB_ + 4096);                         \
    lds16(gB + ko_ + 2 * rowK64, dB_ + 8192);                         \
    lds16(gB + ko_ + 3 * rowK64, dB_ + 12288);                        \
  }

  // prologue: stage K-tiles 0,1; wait tile 0 (8 of 16 retire); publish;
  // issue tile-0 ks0 fragment reads.
  STAGE256(0, 0);
  STAGE256(1, 1);
  asm volatile("s_waitcnt vmcnt(8)" ::: "memory");
  __builtin_amdgcn_s_barrier();
  __builtin_amdgcn_sched_barrier(0);
  read_frags(smA[0], smB[0], wr, wcn, frow, fg0, af0, bf0);
  __builtin_amdgcn_sched_barrier(0);

  for (int kt = 0; kt < nk; ++kt) {
    const int c = kt & 1;
    const unsigned short* pA = smA[c];
    const unsigned short* pB = smB[c];

    // 1. issue ks1 reads (set1) -- fly under MFMA(set0)
    read_frags(pA, pB, wr, wcn, frow, fg0 ^ 4, af1, bf1);
    // 2. set0 complete (in-order DS retire; only set1's 12 may remain)
    asm volatile("s_waitcnt lgkmcnt(12)" ::: "memory");
    __builtin_amdgcn_sched_barrier(0);
    // 3. MFMA ks0 (set1 reads fly underneath)
    __builtin_amdgcn_s_setprio(1);
    mfma32(af0, bf0, acc);
    __builtin_amdgcn_s_setprio(0);
    __builtin_amdgcn_sched_barrier(0);
    // 4. set1 landed (flew under MFMA set0)
    asm volatile("s_waitcnt lgkmcnt(0)" ::: "memory");
    __builtin_amdgcn_sched_barrier(0);
    // 5. WAR barrier: every wave done reading buf c
    __builtin_amdgcn_s_barrier();
    __builtin_amdgcn_sched_barrier(0);
    // 6. stage tile kt+2 into buf c
    if (kt + 2 < nk) STAGE256(kt + 2, c);
    // 7. MFMA ks1 (covers staging issue + kt+1 load latency)
    __builtin_amdgcn_s_setprio(1);
    mfma32(af1, bf1, acc);
    __builtin_amdgcn_s_setprio(0);
    __builtin_amdgcn_sched_barrier(0);
    // 8. wait tile kt+1's loads (leave kt+2's 8 in flight); publish
    if (kt + 2 < nk) {
      asm volatile("s_waitcnt vmcnt(8)" ::: "memory");
    } else if (kt + 1 < nk) {
      asm volatile("s_waitcnt vmcnt(0)" ::: "memory");
    }
    if (kt + 1 < nk) {
      __builtin_amdgcn_s_barrier();
      __builtin_amdgcn_sched_barrier(0);
      // 9. issue next tile's ks0 reads (set0) -- hidden by loop backedge
      read_frags(smA[c ^ 1], smB[c ^ 1], wr, wcn, frow, fg0, af0, bf0);
    }
  }
#undef STAGE256

  // ---- epilogue ----
  const float sw = (float)fmax(meanw[0], 1e-5);
#pragma unroll
  for (int m = 0; m < 8; ++m) {
#pragma unroll
    for (int j = 0; j < 4; ++j) {
      const long row = r0 + wr * 128 + m * 16 + (lane >> 4) * 4 + j;
      const float sa = dsA[row] * sw;
#pragma unroll
      for (int n = 0; n < 4; ++n) {
        const long col = c0 + wcn * 64 + n * 16 + (lane & 15);
        float v = acc[m][n][j] * sa + bias[col];
        if (EPI == 1) {
          float gl = 0.5f * v * (1.0f + erff(v * 0.70710678118654752f));
          outf[row * (long)N + col] = gl;
        } else {
          outf[row * (long)N + col] = v;
        }
      }
    }
  }
}

extern "C" void kernel_launch(void* const* d_in, const int* in_sizes, int n_in,
                              void* d_out, int out_size, void* d_ws, size_t ws_size,
                              hipStream_t stream) {
  const float* x     = (const float*)d_in[0];
  const float* gamma = (const float*)d_in[1];
  const float* beta  = (const float*)d_in[2];
  const float* w1    = (const float*)d_in[3];
  const float* b1    = (const float*)d_in[4];
  const float* w2    = (const float*)d_in[5];
  const float* b2    = (const float*)d_in[6];

  char* ws = (char*)d_ws;
  // meta (<256K): part1@0, part2@16K, means@32K, ds1@64K, ds2@128K
  // [1M)      wq  32M  (wq1, reused for wq2 after last GEMM1 chunk)
  // [1M+32M)  aq  64M
  // [1M+96M)  hq 256M  (dense quantized h, bf16 ints)
  // peak 353 MiB.  d_out (128M) doubles as f32 GELU staging per M-chunk.
  double* part1 = (double*)(ws + 0);
  double* part2 = (double*)(ws + 16384);
  double* means = (double*)(ws + 32768);
  float* ds1  = (float*)(ws + 65536);
  float* ds2  = (float*)(ws + 131072);
  unsigned short* wq = (unsigned short*)(ws + 1048576l);
  unsigned short* aq = (unsigned short*)(ws + 34603008l);
  unsigned short* hq = (unsigned short*)(ws + 101711872l);

  const int NW = 16777216;  // elements in each weight matrix
  float* hstage = (float*)d_out;  // 4096 x 8192 f32 = 128 MiB, dead until GEMM2

  absmean_partial<<<2048, 256, 0, stream>>>(w1, NW, part1);
  absmean_partial<<<2048, 256, 0, stream>>>(w2, NW, part2);
  absmean_final<<<1, 256, 0, stream>>>(part1, 2048, (double)NW, means + 0);
  absmean_final<<<1, 256, 0, stream>>>(part2, 2048, (double)NW, means + 1);
  wquant_kernel<<<16384, 256, 0, stream>>>(w1, means + 0, wq, NW);
  ln_quant_kernel<<<16384, 256, 0, stream>>>(x, gamma, beta, aq, ds1);

  // GEMM1 in 4 M-chunks: f32 gelu -> d_out staging, requant -> dense hq
  for (int c = 0; c < 4; ++c) {
    const long r0 = (long)c * MCHUNK;
    gemm256_kernel<1><<<(H_DIM / 256) * (MCHUNK / 256), 512, 0, stream>>>(
        aq + r0 * D_DIM, wq, ds1 + r0, means + 0, b1, hstage,
        H_DIM / 256, H_DIM, D_DIM);
    hquant32_kernel<<<MCHUNK, 256, 0, stream>>>(
        hstage, hq + r0 * H_DIM, ds2 + r0);
  }

  // wq slot now free: quantize w2 into it
  wquant_kernel<<<16384, 256, 0, stream>>>(w2, means + 1, wq, NW);

  // GEMM2: out = hq . wq2^T * (ds2*sw2) + b2
  gemm256_kernel<2><<<(D_DIM / 256) * (M_DIM / 256), 512, 0, stream>>>(
      hq, wq, ds2, means + 1, b2, (float*)d_out,
      D_DIM / 256, D_DIM, H_DIM);
}

// Round 8
// 1407.228 us; speedup vs baseline: 1.1201x; 1.0054x over previous
//
#include <hip/hip_runtime.h>
#include <hip/hip_bf16.h>

// BitNet FFN: LN -> act_quant/ternary-W matmul -> GELU(erf) -> act_quant/ternary-W matmul
// Shapes: x[4,4096,2048] f32, w1[8192,2048], w2[2048,8192], out [16384,2048] f32.
// R8: full 8-phase schedule (2 K-tiles/iter). Per phase: {ds-read subtile ||
// stage 1 half-tile -> barrier -> lgkm(0) -> 16 MFMA -> barrier}; vmcnt(2)
// counted waits only at phases 4 & 8. LDS layout + per-acc FP order identical
// to R7 -> output bit-identical (absmax 2.539e-2 canary).
// Peak ws 353 MiB; d_out doubles as f32 GELU staging per M-chunk.

typedef __attribute__((ext_vector_type(8))) short short8;
typedef __attribute__((ext_vector_type(4))) float floatx4;

#define D_DIM 2048
#define H_DIM 8192
#define M_DIM 16384
#define MCHUNK 4096

// ---------- small helpers ----------
__device__ __forceinline__ unsigned short f2bf(float f) {
  unsigned int u = __builtin_bit_cast(unsigned int, f);
  u += 0x7FFFu + ((u >> 16) & 1u);   // RNE; inputs here are never NaN
  return (unsigned short)(u >> 16);
}

__device__ __forceinline__ float block_sum(float v, float* buf) {
#pragma unroll
  for (int o = 32; o > 0; o >>= 1) v += __shfl_down(v, o, 64);
  const int lane = threadIdx.x & 63, w = threadIdx.x >> 6;
  if (lane == 0) buf[w] = v;
  __syncthreads();
  float r = buf[0] + buf[1] + buf[2] + buf[3];
  __syncthreads();
  return r;
}
__device__ __forceinline__ float block_max(float v, float* buf) {
#pragma unroll
  for (int o = 32; o > 0; o >>= 1) v = fmaxf(v, __shfl_down(v, o, 64));
  const int lane = threadIdx.x & 63, w = threadIdx.x >> 6;
  if (lane == 0) buf[w] = v;
  __syncthreads();
  float r = fmaxf(fmaxf(buf[0], buf[1]), fmaxf(buf[2], buf[3]));
  __syncthreads();
  return r;
}

__device__ __forceinline__ void lds16(const unsigned short* g, unsigned short* l) {
  __builtin_amdgcn_global_load_lds(
      (const __attribute__((address_space(1))) unsigned int*)g,
      (__attribute__((address_space(3))) unsigned int*)l, 16, 0, 0);
}

// ---------- weight abs-mean (deterministic two-stage) ----------
__global__ __launch_bounds__(256) void absmean_partial(const float* __restrict__ w,
                                                       int n, double* __restrict__ part) {
  __shared__ float buf[4];
  float s = 0.0f;
  const long stride = (long)gridDim.x * 256 * 4;
  for (long i = ((long)blockIdx.x * 256 + threadIdx.x) * 4; i < n; i += stride) {
    float4 v = *(const float4*)(w + i);
    s += fabsf(v.x) + fabsf(v.y) + fabsf(v.z) + fabsf(v.w);
  }
  float r = block_sum(s, buf);
  if (threadIdx.x == 0) part[blockIdx.x] = (double)r;
}

__global__ __launch_bounds__(256) void absmean_final(const double* __restrict__ part,
                                                     int nb, double n, double* __restrict__ out) {
  __shared__ double buf[4];
  double s = 0.0;
  for (int i = threadIdx.x; i < nb; i += 256) s += part[i];
#pragma unroll
  for (int o = 32; o > 0; o >>= 1) s += __shfl_down(s, o, 64);
  const int lane = threadIdx.x & 63, w = threadIdx.x >> 6;
  if (lane == 0) buf[w] = s;
  __syncthreads();
  if (threadIdx.x == 0) out[0] = (buf[0] + buf[1] + buf[2] + buf[3]) / n;
}

// ---------- ternary weight quant: t = clip(rint(w*s),-1,1), stored as bf16 ----------
__global__ __launch_bounds__(256) void wquant_kernel(const float* __restrict__ w,
                                                     const double* __restrict__ mean,
                                                     unsigned short* __restrict__ wq, int n) {
  long i = ((long)blockIdx.x * 256 + threadIdx.x) * 4;
  if (i >= n) return;
  const float s = 1.0f / (float)fmax(mean[0], 1e-5);
  float4 v = *(const float4*)(w + i);
  ushort4 q;
  q.x = f2bf(fminf(fmaxf(rintf(v.x * s), -1.f), 1.f));
  q.y = f2bf(fminf(fmaxf(rintf(v.y * s), -1.f), 1.f));
  q.z = f2bf(fminf(fmaxf(rintf(v.z * s), -1.f), 1.f));
  q.w = f2bf(fminf(fmaxf(rintf(v.w * s), -1.f), 1.f));
  *(ushort4*)(wq + i) = q;
}

// ---------- fused LayerNorm + per-token int8 absmax quant ----------
__global__ __launch_bounds__(256) void ln_quant_kernel(const float* __restrict__ x,
                                                       const float* __restrict__ gamma,
                                                       const float* __restrict__ beta,
                                                       unsigned short* __restrict__ aq,
                                                       float* __restrict__ ds) {
  __shared__ float buf[4];
  const int t = threadIdx.x;
  const long row = blockIdx.x;
  const float* xr = x + row * (long)D_DIM;
  float v[8];
  *(float4*)(v)     = *(const float4*)(xr + t * 8);
  *(float4*)(v + 4) = *(const float4*)(xr + t * 8 + 4);
  float s = 0.f;
#pragma unroll
  for (int i = 0; i < 8; ++i) s += v[i];
  s = block_sum(s, buf);
  const float mu = s * (1.0f / 2048.0f);
  float sq = 0.f;
#pragma unroll
  for (int i = 0; i < 8; ++i) { float d = v[i] - mu; sq += d * d; }
  sq = block_sum(sq, buf);
  const float inv = 1.0f / sqrtf(sq * (1.0f / 2048.0f) + 1e-5f);
  float gam[8], bet[8];
  *(float4*)(gam)     = *(const float4*)(gamma + t * 8);
  *(float4*)(gam + 4) = *(const float4*)(gamma + t * 8 + 4);
  *(float4*)(bet)     = *(const float4*)(beta + t * 8);
  *(float4*)(bet + 4) = *(const float4*)(beta + t * 8 + 4);
  float xn[8]; float am = 0.f;
#pragma unroll
  for (int i = 0; i < 8; ++i) {
    xn[i] = (v[i] - mu) * inv * gam[i] + bet[i];
    am = fmaxf(am, fabsf(xn[i]));
  }
  am = block_max(am, buf);
  am = fmaxf(am, 1e-5f);
  const float qs = 127.0f / am;
  __align__(16) unsigned short q[8];
#pragma unroll
  for (int i = 0; i < 8; ++i)
    q[i] = f2bf(fminf(fmaxf(rintf(xn[i] * qs), -128.f), 127.f));
  *(ushort4*)(aq + row * D_DIM + t * 8)     = *(ushort4*)(q);
  *(ushort4*)(aq + row * D_DIM + t * 8 + 4) = *(ushort4*)(q + 4);
  if (t == 0) ds[row] = am / 127.0f;
}

// ---------- per-token re-quant from f32 h chunk -> dense bf16 ints ----------
__global__ __launch_bounds__(256) void hquant32_kernel(const float* __restrict__ src,
                                                       unsigned short* __restrict__ dst,
                                                       float* __restrict__ ds2) {
  __shared__ float buf[4];
  const int t = threadIdx.x;
  const long row = blockIdx.x;
  const float* sr = src + row * (long)H_DIM;
  float v[4][8];
#pragma unroll
  for (int c = 0; c < 4; ++c) {
    *(float4*)(v[c])     = *(const float4*)(sr + (c * 256 + t) * 8);
    *(float4*)(v[c] + 4) = *(const float4*)(sr + (c * 256 + t) * 8 + 4);
  }
  float am = 0.f;
#pragma unroll
  for (int c = 0; c < 4; ++c)
#pragma unroll
    for (int i = 0; i < 8; ++i) am = fmaxf(am, fabsf(v[c][i]));
  am = block_max(am, buf);
  am = fmaxf(am, 1e-5f);
  const float qs = 127.0f / am;
  unsigned short* dr = dst + row * (long)H_DIM;
#pragma unroll
  for (int c = 0; c < 4; ++c) {
    short8 o;
#pragma unroll
    for (int i = 0; i < 8; ++i)
      o[i] = (short)f2bf(fminf(fmaxf(rintf(v[c][i] * qs), -128.f), 127.f));
    *(short8*)(dr + (c * 256 + t) * 8) = o;
  }
  if (t == 0) ds2[row] = am / 127.0f;
}

// ---------- subtile readers / MFMA quadrant ----------
__device__ __forceinline__ void read_a4(const unsigned short* sm, int base, int frow,
                                        int kg, int f7, short8 (&af)[4][2]) {
#pragma unroll
  for (int ms = 0; ms < 4; ++ms)
#pragma unroll
    for (int ks = 0; ks < 2; ++ks)
      af[ms][ks] = *(const short8*)&sm[base + (ms * 16 + frow) * 64 + ((ks * 4 + kg) ^ f7) * 8];
}
__device__ __forceinline__ void read_b2(const unsigned short* sm, int base, int frow,
                                        int kg, int f7, short8 (&bf)[2][2]) {
#pragma unroll
  for (int ns = 0; ns < 2; ++ns)
#pragma unroll
    for (int ks = 0; ks < 2; ++ks)
      bf[ns][ks] = *(const short8*)&sm[base + (ns * 16 + frow) * 64 + ((ks * 4 + kg) ^ f7) * 8];
}
__device__ __forceinline__ void mfma_q(const short8 (&af)[4][2], const short8 (&bf)[2][2],
                                       floatx4 (&acc)[8][4], int m0, int n0) {
#pragma unroll
  for (int ms = 0; ms < 4; ++ms)
#pragma unroll
    for (int ns = 0; ns < 2; ++ns)
#pragma unroll
      for (int ks = 0; ks < 2; ++ks)
        acc[m0 + ms][n0 + ns] =
            __builtin_amdgcn_mfma_f32_16x16x32_bf16(af[ms][ks], bf[ns][ks], acc[m0 + ms][n0 + ns], 0, 0, 0);
}

// ---------- 256x256 BK=64 8-phase GEMM, A[M,K] x B[N,K]^T ----------
// 8 waves (2M x 4N); double-buffered 128KiB LDS ([dbuf][256][64] per matrix).
// Iteration = 2 K-tiles (t0->buf0, t1->buf1), 8 phases. Stage order:
//   P0:A1(t1) P1:B0(t1) P2:B1(t1) P3:A0(t0+2) P4:A1(t0+2) P5:B0(t0+2)
//   P6:B1(t0+2) P7:A0(t1+2);  vmcnt(2) at end of P3 and P7 only.
// EPI==1: dequant+bias+exact GELU -> f32.  EPI==2: dequant+bias -> f32.
template <int EPI>
__global__ __launch_bounds__(512, 2) void gemm256_kernel(
    const unsigned short* __restrict__ A,
    const unsigned short* __restrict__ Bm,
    const float* __restrict__ dsA,
    const double* __restrict__ meanw,
    const float* __restrict__ bias,
    float* __restrict__ outf,
    int NBX, int N, int K) {
  __shared__ __align__(16) unsigned short smA[2 * 256 * 64];
  __shared__ __align__(16) unsigned short smB[2 * 256 * 64];
  const int tid = threadIdx.x;
  const int lane = tid & 63;
  const int wid = tid >> 6;
  const int wr = wid >> 2;    // 0..1 (M half: 128 rows)
  const int wcn = wid & 3;    // 0..3 (N quarter: 64 cols)

  // T1: XCD-aware bijective block swizzle (gridDim.x % 8 == 0 here: 512)
  const int cpx = gridDim.x >> 3;
  const int swz = ((int)blockIdx.x & 7) * cpx + ((int)blockIdx.x >> 3);
  const int bx = swz % NBX, by = swz / NBX;
  const long r0 = (long)by * 256;
  const long c0 = (long)bx * 256;

  // staging geometry (pre-swizzled source, linear LDS dest — rule #21)
  const int srow = tid >> 3;                       // 0..63
  const int schunk = (tid & 7) ^ (srow & 7);
  const unsigned short* gAs = A + (r0 + srow) * (long)K + schunk * 8;
  const unsigned short* gBs = Bm + (c0 + srow) * (long)K + schunk * 8;

  // fragment-read geometry
  const int frow = lane & 15;
  const int kg = lane >> 4;        // 0..3
  const int f7 = frow & 7;

  floatx4 acc[8][4] = {};
  short8 af[4][2], bf0[2][2], bf1[2][2];
  const int nk = K >> 6;           // BK = 64 K-tiles
  const int nk2 = nk >> 1;

// stage one half-tile (h) of K-tile t of matrix (gbase) into dbuf d of smbase
#define STG(gbase, h, t, smbase, d) {                                                         \
    lds16((gbase) + (long)((h) * 128) * K + (long)(t) * 64,                                   \
          &(smbase)[(d) * 16384 + (h) * 8192 + tid * 8]);                                     \
    lds16((gbase) + (long)((h) * 128 + 64) * K + (long)(t) * 64,                              \
          &(smbase)[(d) * 16384 + (h) * 8192 + tid * 8 + 4096]); }
#define BAR  __builtin_amdgcn_s_barrier()
#define SCB  __builtin_amdgcn_sched_barrier(0)
#define LGKM0 asm volatile("s_waitcnt lgkmcnt(0)" ::: "memory")
#define PRIO1 __builtin_amdgcn_s_setprio(1)
#define PRIO0 __builtin_amdgcn_s_setprio(0)

  // prologue: t0 full (8 loads) + A-h0(t1) (2); drain t0; publish
  STG(gAs, 0, 0, smA, 0); STG(gAs, 1, 0, smA, 0);
  STG(gBs, 0, 0, smB, 0); STG(gBs, 1, 0, smB, 0);
  STG(gAs, 0, 1, smA, 1);
  asm volatile("s_waitcnt vmcnt(2)" ::: "memory");
  SCB; BAR; SCB;

  for (int i = 0; i < nk2; ++i) {
    const int t1 = 2 * i + 1;
    const int tn0 = 2 * i + 2;
    const int tn1 = 2 * i + 3;
    const bool s0 = tn0 < nk, s1 = tn1 < nk;

    // ---- P0: read A(buf0,mh0)+B(buf0,nh0); stage A-h1(t1)->buf1; q(0,0) t0
    read_a4(smA, (wr * 128 + 0) * 64, frow, kg, f7, af);
    read_b2(smB, (wcn * 64 + 0) * 64, frow, kg, f7, bf0);
    STG(gAs, 1, t1, smA, 1);
    SCB; BAR; LGKM0; SCB;
    PRIO1; mfma_q(af, bf0, acc, 0, 0); PRIO0;
    SCB; BAR;

    // ---- P1: read B(buf0,nh1); stage B-h0(t1)->buf1; q(0,1) t0
    read_b2(smB, (wcn * 64 + 32) * 64, frow, kg, f7, bf1);
    STG(gBs, 0, t1, smB, 1);
    SCB; BAR; LGKM0; SCB;
    PRIO1; mfma_q(af, bf1, acc, 0, 2); PRIO0;
    SCB; BAR;

    // ---- P2: read A(buf0,mh1); stage B-h1(t1)->buf1; q(1,1) t0
    read_a4(smA, (wr * 128 + 64) * 64, frow, kg, f7, af);
    STG(gBs, 1, t1, smB, 1);
    SCB; BAR; LGKM0; SCB;
    PRIO1; mfma_q(af, bf1, acc, 4, 2); PRIO0;
    SCB; BAR;

    // ---- P3: stage A-h0(tn0)->buf0 (buf0 reads ended P2); q(1,0) t0; vmcnt
    if (s0) STG(gAs, 0, tn0, smA, 0);
    SCB; BAR; SCB;
    PRIO1; mfma_q(af, bf0, acc, 4, 0); PRIO0;
    SCB;
    if (s0) { asm volatile("s_waitcnt vmcnt(2)" ::: "memory"); }
    else    { asm volatile("s_waitcnt vmcnt(0)" ::: "memory"); }
    SCB; BAR;

    // ---- P4: read A(buf1,mh0)+B(buf1,nh0); stage A-h1(tn0); q(0,0) t1
    read_a4(smA, 16384 + (wr * 128 + 0) * 64, frow, kg, f7, af);
    read_b2(smB, 16384 + (wcn * 64 + 0) * 64, frow, kg, f7, bf0);
    if (s0) STG(gAs, 1, tn0, smA, 0);
    SCB; BAR; LGKM0; SCB;
    PRIO1; mfma_q(af, bf0, acc, 0, 0); PRIO0;
    SCB; BAR;

    // ---- P5: read B(buf1,nh1); stage B-h0(tn0); q(0,1) t1
    read_b2(smB, 16384 + (wcn * 64 + 32) * 64, frow, kg, f7, bf1);
    if (s0) STG(gBs, 0, tn0, smB, 0);
    SCB; BAR; LGKM0; SCB;
    PRIO1; mfma_q(af, bf1, acc, 0, 2); PRIO0;
    SCB; BAR;

    // ---- P6: read A(buf1,mh1); stage B-h1(tn0); q(1,1) t1
    read_a4(smA, 16384 + (wr * 128 + 64) * 64, frow, kg, f7, af);
    if (s0) STG(gBs, 1, tn0, smB, 0);
    SCB; BAR; LGKM0; SCB;
    PRIO1; mfma_q(af, bf1, acc, 4, 2); PRIO0;
    SCB; BAR;

    // ---- P7: stage A-h0(tn1)->buf1 (buf1 reads ended P6); q(1,0) t1; vmcnt
    if (s1) STG(gAs, 0, tn1, smA, 1);
    SCB; BAR; SCB;
    PRIO1; mfma_q(af, bf0, acc, 4, 0); PRIO0;
    SCB;
    if (s1) { asm volatile("s_waitcnt vmcnt(2)" ::: "memory"); }
    else    { asm volatile("s_waitcnt vmcnt(0)" ::: "memory"); }
    SCB; BAR;
  }
#undef STG
#undef BAR
#undef SCB
#undef LGKM0
#undef PRIO1
#undef PRIO0

  // ---- epilogue ----
  const float sw = (float)fmax(meanw[0], 1e-5);
#pragma unroll
  for (int m = 0; m < 8; ++m) {
#pragma unroll
    for (int j = 0; j < 4; ++j) {
      const long row = r0 + wr * 128 + m * 16 + (lane >> 4) * 4 + j;
      const float sa = dsA[row] * sw;
#pragma unroll
      for (int n = 0; n < 4; ++n) {
        const long col = c0 + wcn * 64 + n * 16 + (lane & 15);
        float v = acc[m][n][j] * sa + bias[col];
        if (EPI == 1) {
          float gl = 0.5f * v * (1.0f + erff(v * 0.70710678118654752f));
          outf[row * (long)N + col] = gl;
        } else {
          outf[row * (long)N + col] = v;
        }
      }
    }
  }
}

extern "C" void kernel_launch(void* const* d_in, const int* in_sizes, int n_in,
                              void* d_out, int out_size, void* d_ws, size_t ws_size,
                              hipStream_t stream) {
  const float* x     = (const float*)d_in[0];
  const float* gamma = (const float*)d_in[1];
  const float* beta  = (const float*)d_in[2];
  const float* w1    = (const float*)d_in[3];
  const float* b1    = (const float*)d_in[4];
  const float* w2    = (const float*)d_in[5];
  const float* b2    = (const float*)d_in[6];

  char* ws = (char*)d_ws;
  // meta (<256K): part1@0, part2@16K, means@32K, ds1@64K, ds2@128K
  // [1M)      wq  32M  (wq1, reused for wq2 after last GEMM1 chunk)
  // [1M+32M)  aq  64M
  // [1M+96M)  hq 256M  (dense quantized h, bf16 ints)
  // peak 353 MiB.  d_out (128M) doubles as f32 GELU staging per M-chunk.
  double* part1 = (double*)(ws + 0);
  double* part2 = (double*)(ws + 16384);
  double* means = (double*)(ws + 32768);
  float* ds1  = (float*)(ws + 65536);
  float* ds2  = (float*)(ws + 131072);
  unsigned short* wq = (unsigned short*)(ws + 1048576l);
  unsigned short* aq = (unsigned short*)(ws + 34603008l);
  unsigned short* hq = (unsigned short*)(ws + 101711872l);

  const int NW = 16777216;  // elements in each weight matrix
  float* hstage = (float*)d_out;  // 4096 x 8192 f32 = 128 MiB, dead until GEMM2

  absmean_partial<<<2048, 256, 0, stream>>>(w1, NW, part1);
  absmean_partial<<<2048, 256, 0, stream>>>(w2, NW, part2);
  absmean_final<<<1, 256, 0, stream>>>(part1, 2048, (double)NW, means + 0);
  absmean_final<<<1, 256, 0, stream>>>(part2, 2048, (double)NW, means + 1);
  wquant_kernel<<<16384, 256, 0, stream>>>(w1, means + 0, wq, NW);
  ln_quant_kernel<<<16384, 256, 0, stream>>>(x, gamma, beta, aq, ds1);

  // GEMM1 in 4 M-chunks: f32 gelu -> d_out staging, requant -> dense hq
  for (int c = 0; c < 4; ++c) {
    const long r0 = (long)c * MCHUNK;
    gemm256_kernel<1><<<(H_DIM / 256) * (MCHUNK / 256), 512, 0, stream>>>(
        aq + r0 * D_DIM, wq, ds1 + r0, means + 0, b1, hstage,
        H_DIM / 256, H_DIM, D_DIM);
    hquant32_kernel<<<MCHUNK, 256, 0, stream>>>(
        hstage, hq + r0 * H_DIM, ds2 + r0);
  }

  // wq slot now free: quantize w2 into it
  wquant_kernel<<<16384, 256, 0, stream>>>(w2, means + 1, wq, NW);

  // GEMM2: out = hq . wq2^T * (ds2*sw2) + b2
  gemm256_kernel<2><<<(D_DIM / 256) * (M_DIM / 256), 512, 0, stream>>>(
      hq, wq, ds2, means + 1, b2, (float*)d_out,
      D_DIM / 256, D_DIM, H_DIM);
}

// Round 10
// 989.496 us; speedup vs baseline: 1.5929x; 1.4222x over previous
//
#include <hip/hip_runtime.h>
#include <hip/hip_bf16.h>

// BitNet FFN: LN -> act_quant/ternary-W matmul -> GELU(erf) -> act_quant/ternary-W matmul
// Shapes: x[4,4096,2048] f32, w1[8192,2048], w2[2048,8192], out [16384,2048] f32.
// R10: R9 (int8 end-to-end, v_mfma_i32_16x16x64_i8) with the LDS double-buffer
// stride bug fixed: dbuf stride is 16384 BYTES (R9 kept R8's 32768 from the
// short-element layout -> buf1 writes/reads landed outside smA, corrupting smB).
// i32 accum exact; (float)acc exact -> output bit-identical (absmax 2.539e-2).
// Peak ws 177 MiB; d_out doubles as f32 GELU staging per M-chunk.

typedef __attribute__((ext_vector_type(8))) short short8;
typedef __attribute__((ext_vector_type(4))) int int4v;

#define D_DIM 2048
#define H_DIM 8192
#define M_DIM 16384
#define MCHUNK 4096

// ---------- small helpers ----------
__device__ __forceinline__ float block_sum(float v, float* buf) {
#pragma unroll
  for (int o = 32; o > 0; o >>= 1) v += __shfl_down(v, o, 64);
  const int lane = threadIdx.x & 63, w = threadIdx.x >> 6;
  if (lane == 0) buf[w] = v;
  __syncthreads();
  float r = buf[0] + buf[1] + buf[2] + buf[3];
  __syncthreads();
  return r;
}
__device__ __forceinline__ float block_max(float v, float* buf) {
#pragma unroll
  for (int o = 32; o > 0; o >>= 1) v = fmaxf(v, __shfl_down(v, o, 64));
  const int lane = threadIdx.x & 63, w = threadIdx.x >> 6;
  if (lane == 0) buf[w] = v;
  __syncthreads();
  float r = fmaxf(fmaxf(buf[0], buf[1]), fmaxf(buf[2], buf[3]));
  __syncthreads();
  return r;
}

__device__ __forceinline__ void lds16(const signed char* g, signed char* l) {
  __builtin_amdgcn_global_load_lds(
      (const __attribute__((address_space(1))) unsigned int*)g,
      (__attribute__((address_space(3))) unsigned int*)l, 16, 0, 0);
}

// ---------- weight abs-mean (deterministic two-stage) ----------
__global__ __launch_bounds__(256) void absmean_partial(const float* __restrict__ w,
                                                       int n, double* __restrict__ part) {
  __shared__ float buf[4];
  float s = 0.0f;
  const long stride = (long)gridDim.x * 256 * 4;
  for (long i = ((long)blockIdx.x * 256 + threadIdx.x) * 4; i < n; i += stride) {
    float4 v = *(const float4*)(w + i);
    s += fabsf(v.x) + fabsf(v.y) + fabsf(v.z) + fabsf(v.w);
  }
  float r = block_sum(s, buf);
  if (threadIdx.x == 0) part[blockIdx.x] = (double)r;
}

__global__ __launch_bounds__(256) void absmean_final(const double* __restrict__ part,
                                                     int nb, double n, double* __restrict__ out) {
  __shared__ double buf[4];
  double s = 0.0;
  for (int i = threadIdx.x; i < nb; i += 256) s += part[i];
#pragma unroll
  for (int o = 32; o > 0; o >>= 1) s += __shfl_down(s, o, 64);
  const int lane = threadIdx.x & 63, w = threadIdx.x >> 6;
  if (lane == 0) buf[w] = s;
  __syncthreads();
  if (threadIdx.x == 0) out[0] = (buf[0] + buf[1] + buf[2] + buf[3]) / n;
}

// ---------- ternary weight quant -> i8 {-1,0,1} ----------
__global__ __launch_bounds__(256) void wquant_kernel(const float* __restrict__ w,
                                                     const double* __restrict__ mean,
                                                     signed char* __restrict__ wq, int n) {
  long i = ((long)blockIdx.x * 256 + threadIdx.x) * 4;
  if (i >= n) return;
  const float s = 1.0f / (float)fmax(mean[0], 1e-5);
  float4 v = *(const float4*)(w + i);
  __align__(4) signed char q[4];
  q[0] = (signed char)(int)fminf(fmaxf(rintf(v.x * s), -1.f), 1.f);
  q[1] = (signed char)(int)fminf(fmaxf(rintf(v.y * s), -1.f), 1.f);
  q[2] = (signed char)(int)fminf(fmaxf(rintf(v.z * s), -1.f), 1.f);
  q[3] = (signed char)(int)fminf(fmaxf(rintf(v.w * s), -1.f), 1.f);
  *(int*)(wq + i) = *(int*)q;
}

// ---------- fused LayerNorm + per-token int8 absmax quant -> i8 ----------
__global__ __launch_bounds__(256) void ln_quant_kernel(const float* __restrict__ x,
                                                       const float* __restrict__ gamma,
                                                       const float* __restrict__ beta,
                                                       signed char* __restrict__ aq,
                                                       float* __restrict__ ds) {
  __shared__ float buf[4];
  const int t = threadIdx.x;
  const long row = blockIdx.x;
  const float* xr = x + row * (long)D_DIM;
  float v[8];
  *(float4*)(v)     = *(const float4*)(xr + t * 8);
  *(float4*)(v + 4) = *(const float4*)(xr + t * 8 + 4);
  float s = 0.f;
#pragma unroll
  for (int i = 0; i < 8; ++i) s += v[i];
  s = block_sum(s, buf);
  const float mu = s * (1.0f / 2048.0f);
  float sq = 0.f;
#pragma unroll
  for (int i = 0; i < 8; ++i) { float d = v[i] - mu; sq += d * d; }
  sq = block_sum(sq, buf);
  const float inv = 1.0f / sqrtf(sq * (1.0f / 2048.0f) + 1e-5f);
  float gam[8], bet[8];
  *(float4*)(gam)     = *(const float4*)(gamma + t * 8);
  *(float4*)(gam + 4) = *(const float4*)(gamma + t * 8 + 4);
  *(float4*)(bet)     = *(const float4*)(beta + t * 8);
  *(float4*)(bet + 4) = *(const float4*)(beta + t * 8 + 4);
  float xn[8]; float am = 0.f;
#pragma unroll
  for (int i = 0; i < 8; ++i) {
    xn[i] = (v[i] - mu) * inv * gam[i] + bet[i];
    am = fmaxf(am, fabsf(xn[i]));
  }
  am = block_max(am, buf);
  am = fmaxf(am, 1e-5f);
  const float qs = 127.0f / am;
  __align__(8) signed char q[8];
#pragma unroll
  for (int i = 0; i < 8; ++i)
    q[i] = (signed char)(int)fminf(fmaxf(rintf(xn[i] * qs), -128.f), 127.f);
  *(long*)(aq + row * D_DIM + t * 8) = *(long*)q;
  if (t == 0) ds[row] = am / 127.0f;
}

// ---------- per-token re-quant from f32 h chunk -> dense i8 ----------
__global__ __launch_bounds__(256) void hquant32_kernel(const float* __restrict__ src,
                                                       signed char* __restrict__ dst,
                                                       float* __restrict__ ds2) {
  __shared__ float buf[4];
  const int t = threadIdx.x;
  const long row = blockIdx.x;
  const float* sr = src + row * (long)H_DIM;
  float v[4][8];
#pragma unroll
  for (int c = 0; c < 4; ++c) {
    *(float4*)(v[c])     = *(const float4*)(sr + (c * 256 + t) * 8);
    *(float4*)(v[c] + 4) = *(const float4*)(sr + (c * 256 + t) * 8 + 4);
  }
  float am = 0.f;
#pragma unroll
  for (int c = 0; c < 4; ++c)
#pragma unroll
    for (int i = 0; i < 8; ++i) am = fmaxf(am, fabsf(v[c][i]));
  am = block_max(am, buf);
  am = fmaxf(am, 1e-5f);
  const float qs = 127.0f / am;
  signed char* dr = dst + row * (long)H_DIM;
#pragma unroll
  for (int c = 0; c < 4; ++c) {
    __align__(8) signed char o[8];
#pragma unroll
    for (int i = 0; i < 8; ++i)
      o[i] = (signed char)(int)fminf(fmaxf(rintf(v[c][i] * qs), -128.f), 127.f);
    *(long*)(dr + (c * 256 + t) * 8) = *(long*)o;
  }
  if (t == 0) ds2[row] = am / 127.0f;
}

// ---------- subtile readers / MFMA quadrant (i8, K=64 per instr) ----------
__device__ __forceinline__ void read_a4(const signed char* sm, int base, int4v (&af)[4]) {
#pragma unroll
  for (int ms = 0; ms < 4; ++ms)
    af[ms] = *(const int4v*)&sm[base + ms * 1024];   // 16 rows * 64B
}
__device__ __forceinline__ void read_b2(const signed char* sm, int base, int4v (&bf)[2]) {
#pragma unroll
  for (int ns = 0; ns < 2; ++ns)
    bf[ns] = *(const int4v*)&sm[base + ns * 1024];
}
__device__ __forceinline__ void mfma_q(const int4v (&af)[4], const int4v (&bf)[2],
                                       int4v (&acc)[8][4], int m0, int n0) {
#pragma unroll
  for (int ms = 0; ms < 4; ++ms)
#pragma unroll
    for (int ns = 0; ns < 2; ++ns)
      acc[m0 + ms][n0 + ns] = __builtin_amdgcn_mfma_i32_16x16x64_i8(
          af[ms], bf[ns], acc[m0 + ms][n0 + ns], 0, 0, 0);
}

// ---------- 256x256 BK=64 8-phase i8 GEMM, A[M,K] x B[N,K]^T ----------
// 8 waves (2M x 4N); double-buffered 64KiB LDS total.
// Byte layout per matrix: [dbuf(16384B)][half(8192B)][row 0..127][64B row].
// LDS swizzle: chunk ^= (row&3)^((row>>2)&3) (<=2-way, free); applied on the
// pre-swizzled global source AND the ds_read side (rule #21).
// Iteration = 2 K-tiles, 8 phases; 1 load per STG; vmcnt(1) at P3/P7.
// EPI==1: dequant+bias+exact GELU -> f32.  EPI==2: dequant+bias -> f32.
template <int EPI>
__global__ __launch_bounds__(512, 2) void gemm256_kernel(
    const signed char* __restrict__ A,
    const signed char* __restrict__ Bm,
    const float* __restrict__ dsA,
    const double* __restrict__ meanw,
    const float* __restrict__ bias,
    float* __restrict__ outf,
    int NBX, int N, int K) {
  __shared__ __align__(16) signed char smA[2 * 256 * 64];
  __shared__ __align__(16) signed char smB[2 * 256 * 64];
  const int tid = threadIdx.x;
  const int lane = tid & 63;
  const int wid = tid >> 6;
  const int wr = wid >> 2;    // 0..1 (M half: 128 rows)
  const int wcn = wid & 3;    // 0..3 (N quarter: 64 cols)

  // T1: XCD-aware bijective block swizzle (gridDim.x % 8 == 0 here: 512)
  const int cpx = gridDim.x >> 3;
  const int swz = ((int)blockIdx.x & 7) * cpx + ((int)blockIdx.x >> 3);
  const int bx = swz % NBX, by = swz / NBX;
  const long r0 = (long)by * 256;
  const long c0 = (long)bx * 256;

  // staging geometry: half-tile = 128 rows x 64B = 8KB = 512 threads x 16B.
  // thread t -> (row = t>>2, chunk = t&3); source chunk pre-swizzled.
  const int srow = tid >> 2;
  const int schunk = (tid & 3) ^ (srow & 3) ^ ((srow >> 2) & 3);
  const signed char* gAs = A + (r0 + srow) * (long)K + schunk * 16;
  const signed char* gBs = Bm + (c0 + srow) * (long)K + schunk * 16;

  // fragment-read geometry: lane reads row (base+frow), 16B chunk (lane>>4)^swz
  const int frow = lane & 15;
  const int fchunk = (lane >> 4) ^ (frow & 3) ^ ((frow >> 2) & 3);
  const int fbyte = frow * 64 + fchunk * 16;
  const int baseA = wr * 8192 + fbyte;                             // + d*16384 + mh*4096
  const int baseB = (wcn >> 1) * 8192 + (wcn & 1) * 4096 + fbyte;  // + d*16384 + nh*2048

  int4v acc[8][4] = {};
  int4v af[4], bf0[2], bf1[2];
  const int nk = K >> 6;           // BK = 64 K-tiles
  const int nk2 = nk >> 1;

// stage half-tile h of K-tile t into dbuf d (1 global_load_lds per thread)
#define STG(gbase, h, t, smbase, d)                                           \
    lds16((gbase) + (long)((h) * 128) * K + (long)(t) * 64,                   \
          &(smbase)[(d) * 16384 + (h) * 8192 + tid * 16]);
#define BAR  __builtin_amdgcn_s_barrier()
#define SCB  __builtin_amdgcn_sched_barrier(0)
#define LGKM0 asm volatile("s_waitcnt lgkmcnt(0)" ::: "memory")
#define PRIO1 __builtin_amdgcn_s_setprio(1)
#define PRIO0 __builtin_amdgcn_s_setprio(0)

  // prologue: t0 full (4 loads) + A-h0(t1); drain t0 (leave 1); publish
  STG(gAs, 0, 0, smA, 0); STG(gAs, 1, 0, smA, 0);
  STG(gBs, 0, 0, smB, 0); STG(gBs, 1, 0, smB, 0);
  STG(gAs, 0, 1, smA, 1);
  asm volatile("s_waitcnt vmcnt(1)" ::: "memory");
  SCB; BAR; SCB;

  for (int i = 0; i < nk2; ++i) {
    const int t1 = 2 * i + 1;
    const int tn0 = 2 * i + 2;
    const int tn1 = 2 * i + 3;
    const bool s0 = tn0 < nk, s1 = tn1 < nk;

    // ---- P0: read A(buf0,mh0)+B(buf0,nh0); stage A-h1(t1)->buf1; q(0,0)
    read_a4(smA, baseA, af);
    read_b2(smB, baseB, bf0);
    STG(gAs, 1, t1, smA, 1);
    SCB; BAR; LGKM0; SCB;
    PRIO1; mfma_q(af, bf0, acc, 0, 0); PRIO0;
    SCB; BAR;

    // ---- P1: read B(buf0,nh1); stage B-h0(t1)->buf1; q(0,1)
    read_b2(smB, baseB + 2048, bf1);
    STG(gBs, 0, t1, smB, 1);
    SCB; BAR; LGKM0; SCB;
    PRIO1; mfma_q(af, bf1, acc, 0, 2); PRIO0;
    SCB; BAR;

    // ---- P2: read A(buf0,mh1); stage B-h1(t1)->buf1; q(1,1)
    read_a4(smA, baseA + 4096, af);
    STG(gBs, 1, t1, smB, 1);
    SCB; BAR; LGKM0; SCB;
    PRIO1; mfma_q(af, bf1, acc, 4, 2); PRIO0;
    SCB; BAR;

    // ---- P3: stage A-h0(tn0)->buf0 (buf0 reads ended P2); q(1,0); vmcnt
    if (s0) STG(gAs, 0, tn0, smA, 0);
    SCB; BAR; SCB;
    PRIO1; mfma_q(af, bf0, acc, 4, 0); PRIO0;
    SCB;
    if (s0) { asm volatile("s_waitcnt vmcnt(1)" ::: "memory"); }
    else    { asm volatile("s_waitcnt vmcnt(0)" ::: "memory"); }
    SCB; BAR;

    // ---- P4: read A(buf1,mh0)+B(buf1,nh0); stage A-h1(tn0); q(0,0)
    read_a4(smA, 16384 + baseA, af);
    read_b2(smB, 16384 + baseB, bf0);
    if (s0) STG(gAs, 1, tn0, smA, 0);
    SCB; BAR; LGKM0; SCB;
    PRIO1; mfma_q(af, bf0, acc, 0, 0); PRIO0;
    SCB; BAR;

    // ---- P5: read B(buf1,nh1); stage B-h0(tn0); q(0,1)
    read_b2(smB, 16384 + baseB + 2048, bf1);
    if (s0) STG(gBs, 0, tn0, smB, 0);
    SCB; BAR; LGKM0; SCB;
    PRIO1; mfma_q(af, bf1, acc, 0, 2); PRIO0;
    SCB; BAR;

    // ---- P6: read A(buf1,mh1); stage B-h1(tn0); q(1,1)
    read_a4(smA, 16384 + baseA + 4096, af);
    if (s0) STG(gBs, 1, tn0, smB, 0);
    SCB; BAR; LGKM0; SCB;
    PRIO1; mfma_q(af, bf1, acc, 4, 2); PRIO0;
    SCB; BAR;

    // ---- P7: stage A-h0(tn1)->buf1 (buf1 reads ended P6); q(1,0); vmcnt
    if (s1) STG(gAs, 0, tn1, smA, 1);
    SCB; BAR; SCB;
    PRIO1; mfma_q(af, bf0, acc, 4, 0); PRIO0;
    SCB;
    if (s1) { asm volatile("s_waitcnt vmcnt(1)" ::: "memory"); }
    else    { asm volatile("s_waitcnt vmcnt(0)" ::: "memory"); }
    SCB; BAR;
  }
#undef STG
#undef BAR
#undef SCB
#undef LGKM0
#undef PRIO1
#undef PRIO0

  // ---- epilogue ----
  const float sw = (float)fmax(meanw[0], 1e-5);
#pragma unroll
  for (int m = 0; m < 8; ++m) {
#pragma unroll
    for (int j = 0; j < 4; ++j) {
      const long row = r0 + wr * 128 + m * 16 + (lane >> 4) * 4 + j;
      const float sa = dsA[row] * sw;
#pragma unroll
      for (int n = 0; n < 4; ++n) {
        const long col = c0 + wcn * 64 + n * 16 + (lane & 15);
        float v = (float)acc[m][n][j] * sa + bias[col];
        if (EPI == 1) {
          float gl = 0.5f * v * (1.0f + erff(v * 0.70710678118654752f));
          outf[row * (long)N + col] = gl;
        } else {
          outf[row * (long)N + col] = v;
        }
      }
    }
  }
}

extern "C" void kernel_launch(void* const* d_in, const int* in_sizes, int n_in,
                              void* d_out, int out_size, void* d_ws, size_t ws_size,
                              hipStream_t stream) {
  const float* x     = (const float*)d_in[0];
  const float* gamma = (const float*)d_in[1];
  const float* beta  = (const float*)d_in[2];
  const float* w1    = (const float*)d_in[3];
  const float* b1    = (const float*)d_in[4];
  const float* w2    = (const float*)d_in[5];
  const float* b2    = (const float*)d_in[6];

  char* ws = (char*)d_ws;
  // meta (<256K): part1@0, part2@16K, means@32K, ds1@64K, ds2@128K
  // [1M)       wq  16M i8  (wq1, reused for wq2 after last GEMM1 chunk)
  // [1M+16M)   aq  32M i8
  // [1M+48M)   hq 128M i8  (dense quantized h)
  // peak 177 MiB.  d_out (128M) doubles as f32 GELU staging per M-chunk.
  double* part1 = (double*)(ws + 0);
  double* part2 = (double*)(ws + 16384);
  double* means = (double*)(ws + 32768);
  float* ds1  = (float*)(ws + 65536);
  float* ds2  = (float*)(ws + 131072);
  signed char* wq = (signed char*)(ws + 1048576l);
  signed char* aq = (signed char*)(ws + 17825792l);
  signed char* hq = (signed char*)(ws + 51380224l);

  const int NW = 16777216;  // elements in each weight matrix
  float* hstage = (float*)d_out;  // 4096 x 8192 f32 = 128 MiB, dead until GEMM2

  absmean_partial<<<2048, 256, 0, stream>>>(w1, NW, part1);
  absmean_partial<<<2048, 256, 0, stream>>>(w2, NW, part2);
  absmean_final<<<1, 256, 0, stream>>>(part1, 2048, (double)NW, means + 0);
  absmean_final<<<1, 256, 0, stream>>>(part2, 2048, (double)NW, means + 1);
  wquant_kernel<<<16384, 256, 0, stream>>>(w1, means + 0, wq, NW);
  ln_quant_kernel<<<16384, 256, 0, stream>>>(x, gamma, beta, aq, ds1);

  // GEMM1 in 4 M-chunks: f32 gelu -> d_out staging, requant -> dense i8 hq
  for (int c = 0; c < 4; ++c) {
    const long r0 = (long)c * MCHUNK;
    gemm256_kernel<1><<<(H_DIM / 256) * (MCHUNK / 256), 512, 0, stream>>>(
        aq + r0 * D_DIM, wq, ds1 + r0, means + 0, b1, hstage,
        H_DIM / 256, H_DIM, D_DIM);
    hquant32_kernel<<<MCHUNK, 256, 0, stream>>>(
        hstage, hq + r0 * H_DIM, ds2 + r0);
  }

  // wq slot now free: quantize w2 into it
  wquant_kernel<<<16384, 256, 0, stream>>>(w2, means + 1, wq, NW);

  // GEMM2: out = hq . wq2^T * (ds2*sw2) + b2
  gemm256_kernel<2><<<(D_DIM / 256) * (M_DIM / 256), 512, 0, stream>>>(
      hq, wq, ds2, means + 1, b2, (float*)d_out,
      D_DIM / 256, D_DIM, H_DIM);
}